// Round 5
// baseline (447.614 us; speedup 1.0000x reference)
//
#include <hip/hip_runtime.h>
#include <stdint.h>

typedef unsigned short u16;

#define S_ 4096
#define B_ 8
#define H_ 1024
#define F_ 1024
#define M_ (S_ * B_)   // 32768
#define N_ F_          // 1024
#define K_ H_          // 1024

#define BM 128
#define BN 128
#define BK 64

typedef short short8 __attribute__((ext_vector_type(8)));
typedef float floatx4 __attribute__((ext_vector_type(4)));
typedef unsigned short ushortx4 __attribute__((ext_vector_type(4)));

// RNE float -> bf16 bits (values are well-behaved: no NaN/Inf in this problem)
__device__ __forceinline__ u16 f2bf(float f) {
    union { float f; uint32_t u; } c;
    c.f = f;
    uint32_t u = c.u;
    uint32_t r = (u + 0x7fffu + ((u >> 16) & 1u)) >> 16;
    return (u16)r;
}

// async 16B/lane global -> LDS (dest = wave-uniform base + lane*16)
__device__ __forceinline__ void async_load16(const void* gptr, void* lptr) {
    __builtin_amdgcn_global_load_lds(
        (const __attribute__((address_space(1))) uint32_t*)gptr,
        (__attribute__((address_space(3))) uint32_t*)lptr,
        16 /*size*/, 0 /*offset*/, 0 /*aux*/);
}

// ---------------------------------------------------------------------------
// Kernel 1: transpose + cast W (K_ x N_ fp32, row-major) -> Bt (N_ x K_ bf16)
// (unchanged, verified)
// ---------------------------------------------------------------------------
__global__ __launch_bounds__(256) void transpose_cast_kernel(
    const float* __restrict__ w, u16* __restrict__ bt)
{
    __shared__ float tile[32][33];
    const int tx = threadIdx.x;  // 0..31
    const int ty = threadIdx.y;  // 0..7
    const int n0 = blockIdx.x * 32;
    const int k0 = blockIdx.y * 32;
#pragma unroll
    for (int j = 0; j < 4; ++j)
        tile[ty + j * 8][tx] = w[(size_t)(k0 + ty + j * 8) * N_ + n0 + tx];
    __syncthreads();
#pragma unroll
    for (int j = 0; j < 4; ++j)
        bt[(size_t)(n0 + ty + j * 8) * K_ + k0 + tx] =
            f2bf(tile[tx][ty + j * 8]);
}

// ---------------------------------------------------------------------------
// Kernel 2: LayerNorm — r0 block-per-row version (measured best; the r1
// wave-per-row variant was +16.5 µs). One block (256 threads) per row.
// Only change vs r0: nontemporal stores for ln_out / ln_bf16 (write-once
// streams; L2 is 4 MiB/XCD so allocating 192 MiB of writes there only
// evicts useful lines). NT via ext_vector_type (HIP_vector_type float4 is
// a class -> builtin rejects it; this emits global_store_dwordx4 ... nt).
// ---------------------------------------------------------------------------
__global__ __launch_bounds__(256) void ln_kernel(
    const float* __restrict__ x, const float* __restrict__ scale,
    const float* __restrict__ bias, float* __restrict__ ln_out,
    u16* __restrict__ ln_bf16)
{
    const int row = blockIdx.x;
    const int tid = threadIdx.x;
    const float4 v = reinterpret_cast<const float4*>(x + (size_t)row * H_)[tid];

    float s  = v.x + v.y + v.z + v.w;
    float sq = v.x * v.x + v.y * v.y + v.z * v.z + v.w * v.w;
#pragma unroll
    for (int off = 32; off >= 1; off >>= 1) {
        s  += __shfl_down(s, off, 64);
        sq += __shfl_down(sq, off, 64);
    }
    __shared__ float red[8];
    const int wave = tid >> 6, lane = tid & 63;
    if (lane == 0) { red[wave] = s; red[4 + wave] = sq; }
    __syncthreads();
    const float Ssum = red[0] + red[1] + red[2] + red[3];
    const float Qsum = red[4] + red[5] + red[6] + red[7];
    const float mu   = Ssum * (1.0f / H_);
    const float var  = Qsum * (1.0f / H_) - mu * mu;
    const float rstd = rsqrtf(var + 1e-6f);

    const float4 sc = reinterpret_cast<const float4*>(scale)[tid];
    const float4 bi = reinterpret_cast<const float4*>(bias)[tid];
    floatx4 y;
    y.x = (v.x - mu) * rstd * sc.x + bi.x;
    y.y = (v.y - mu) * rstd * sc.y + bi.y;
    y.z = (v.z - mu) * rstd * sc.z + bi.z;
    y.w = (v.w - mu) * rstd * sc.w + bi.w;

    __builtin_nontemporal_store(
        y, reinterpret_cast<floatx4*>(ln_out + (size_t)row * H_) + tid);

    ushortx4 h;
    h.x = f2bf(y.x); h.y = f2bf(y.y); h.z = f2bf(y.z); h.w = f2bf(y.w);
    __builtin_nontemporal_store(
        h, reinterpret_cast<ushortx4*>(ln_bf16 + (size_t)row * H_) + tid);
}

// ---------------------------------------------------------------------------
// Kernel 3: GEMM C = A * Bt^T — exact r0 structure (measured best).
// 128x128 block tile, BK=64, 4 waves 2x2, 64x64/wave via 4x4
// mfma_f32_16x16x32_bf16, global_load_lds 16B staging, 32 KiB LDS
// -> ~3 blocks/CU; inter-block overlap forgives the barrier drain (m114).
// XOR chunk swizzle via pre-swizzled global source; XCD-swizzled 1-D grid.
// Only change vs r0: nontemporal C stores — C (128 MiB, write-once) was
// evicting the 2 MiB Bt panel + A stream from the 4 MiB per-XCD L2 that the
// XCD swizzle tries to keep resident.
// ---------------------------------------------------------------------------
__global__ __launch_bounds__(256) void gemm_bt_kernel(
    const u16* __restrict__ A, const u16* __restrict__ Bt,
    float* __restrict__ C)
{
    __shared__ __align__(16) u16 As[BM * BK];
    __shared__ __align__(16) u16 Bs[BN * BK];

    const int tid  = threadIdx.x;
    const int wave = tid >> 6;
    const int lane = tid & 63;
    const int wm   = wave >> 1;  // 0..1
    const int wn   = wave & 1;   // 0..1

    // XCD swizzle: by = (bid>>6)*8 + (bid&7), bx = (bid>>3)&7
    const int bid  = blockIdx.x;
    const int bx   = (bid >> 3) & 7;
    const int by   = ((bid >> 6) << 3) | (bid & 7);
    const int row0 = by * BM;
    const int col0 = bx * BN;

    floatx4 acc[4][4];
#pragma unroll
    for (int i = 0; i < 4; ++i)
#pragma unroll
        for (int j = 0; j < 4; ++j) acc[i][j] = (floatx4)0.0f;

    // staging: per call each wave fills 8 rows (64 lanes * 16B = 8 rows * 128B)
    // lane (r=lane>>3, c=lane&7) fetches global chunk (c ^ r) of row r
    const int srow = wave * 8 + (lane >> 3);             // row within 32-row group
    const int scol = (((lane & 7) ^ (lane >> 3)) * 8);   // swizzled bf16 col
    const u16* Ag = A + (size_t)(row0 + srow) * K_ + scol;
    const u16* Bg = Bt + (size_t)(col0 + srow) * K_ + scol;
    char* AsBase = (char*)As + (size_t)(wave * 8) * (BK * 2);
    char* BsBase = (char*)Bs + (size_t)(wave * 8) * (BK * 2);

    for (int kt = 0; kt < K_ / BK; ++kt) {
        const int k0 = kt * BK;
#pragma unroll
        for (int i = 0; i < 4; ++i) {
            async_load16(Ag + (size_t)(i * 32) * K_ + k0,
                         AsBase + (size_t)(i * 32) * (BK * 2));
            async_load16(Bg + (size_t)(i * 32) * K_ + k0,
                         BsBase + (size_t)(i * 32) * (BK * 2));
        }
        __syncthreads();  // drains vmcnt -> LDS tiles complete

#pragma unroll
        for (int ks = 0; ks < 2; ++ks) {
            short8 af[4], bf[4];
#pragma unroll
            for (int mt = 0; mt < 4; ++mt) {
                const int r = wm * 64 + mt * 16 + (lane & 15);
                const int q = ks * 4 + (lane >> 4);       // 16B chunk index
                const int c = q ^ (r & 7);                // XOR de-swizzle
                af[mt] = *reinterpret_cast<const short8*>(
                    (const char*)As + (size_t)r * (BK * 2) + c * 16);
            }
#pragma unroll
            for (int nt = 0; nt < 4; ++nt) {
                const int r = wn * 64 + nt * 16 + (lane & 15);
                const int q = ks * 4 + (lane >> 4);
                const int c = q ^ (r & 7);
                bf[nt] = *reinterpret_cast<const short8*>(
                    (const char*)Bs + (size_t)r * (BK * 2) + c * 16);
            }
#pragma unroll
            for (int mt = 0; mt < 4; ++mt)
#pragma unroll
                for (int nt = 0; nt < 4; ++nt)
                    acc[mt][nt] = __builtin_amdgcn_mfma_f32_16x16x32_bf16(
                        af[mt], bf[nt], acc[mt][nt], 0, 0, 0);
        }
        __syncthreads();  // protect LDS from next iteration's staging
    }

    // epilogue: C/D layout col = lane&15, row = (lane>>4)*4 + reg
#pragma unroll
    for (int mt = 0; mt < 4; ++mt) {
#pragma unroll
        for (int nt = 0; nt < 4; ++nt) {
            const int r0 = row0 + wm * 64 + mt * 16 + (lane >> 4) * 4;
            const int c  = col0 + wn * 64 + nt * 16 + (lane & 15);
#pragma unroll
            for (int r = 0; r < 4; ++r)
                __builtin_nontemporal_store(
                    acc[mt][nt][r], &C[(size_t)(r0 + r) * N_ + c]);
        }
    }
}

// ---------------------------------------------------------------------------
extern "C" void kernel_launch(void* const* d_in, const int* in_sizes, int n_in,
                              void* d_out, int out_size, void* d_ws, size_t ws_size,
                              hipStream_t stream) {
    const float* x      = (const float*)d_in[0];   // (S,B,H)
    const float* scale  = (const float*)d_in[1];   // (H,)
    const float* lnbias = (const float*)d_in[2];   // (H,)
    const float* weight = (const float*)d_in[3];   // (H,F)

    float* out    = (float*)d_out;                     // (S,B,F)
    float* ln_out = (float*)d_out + (size_t)M_ * N_;   // (S,B,H)

    // workspace: [A bf16: M_*K_ u16 = 64 MiB][Bt bf16: N_*K_ u16 = 2 MiB]
    u16* ln_bf16 = (u16*)d_ws;
    u16* bt      = (u16*)d_ws + (size_t)M_ * K_;

    transpose_cast_kernel<<<dim3(N_ / 32, K_ / 32), dim3(32, 8), 0, stream>>>(
        weight, bt);
    ln_kernel<<<M_, 256, 0, stream>>>(x, scale, lnbias, ln_out, ln_bf16);
    gemm_bt_kernel<<<(M_ / BM) * (N_ / BN), 256, 0, stream>>>(ln_bf16, bt, out);
}

// Round 6
// 424.817 us; speedup vs baseline: 1.0537x; 1.0537x over previous
//
#include <hip/hip_runtime.h>
#include <stdint.h>

typedef unsigned short u16;

#define S_ 4096
#define B_ 8
#define H_ 1024
#define F_ 1024
#define M_ (S_ * B_)   // 32768
#define N_ F_          // 1024
#define K_ H_          // 1024

#define BM 128
#define BN 128
#define BK 64

typedef short short8 __attribute__((ext_vector_type(8)));
typedef float floatx4 __attribute__((ext_vector_type(4)));

// RNE float -> bf16 bits (values are well-behaved: no NaN/Inf in this problem)
__device__ __forceinline__ u16 f2bf(float f) {
    union { float f; uint32_t u; } c;
    c.f = f;
    uint32_t u = c.u;
    uint32_t r = (u + 0x7fffu + ((u >> 16) & 1u)) >> 16;
    return (u16)r;
}

// async 16B/lane global -> LDS (dest = wave-uniform base + lane*16)
__device__ __forceinline__ void async_load16(const void* gptr, void* lptr) {
    __builtin_amdgcn_global_load_lds(
        (const __attribute__((address_space(1))) uint32_t*)gptr,
        (__attribute__((address_space(3))) uint32_t*)lptr,
        16 /*size*/, 0 /*offset*/, 0 /*aux*/);
}

// ---------------------------------------------------------------------------
// Kernel 1: transpose + cast W (K_ x N_ fp32, row-major) -> Bt (N_ x K_ bf16)
// (unchanged, verified)
// ---------------------------------------------------------------------------
__global__ __launch_bounds__(256) void transpose_cast_kernel(
    const float* __restrict__ w, u16* __restrict__ bt)
{
    __shared__ float tile[32][33];
    const int tx = threadIdx.x;  // 0..31
    const int ty = threadIdx.y;  // 0..7
    const int n0 = blockIdx.x * 32;
    const int k0 = blockIdx.y * 32;
#pragma unroll
    for (int j = 0; j < 4; ++j)
        tile[ty + j * 8][tx] = w[(size_t)(k0 + ty + j * 8) * N_ + n0 + tx];
    __syncthreads();
#pragma unroll
    for (int j = 0; j < 4; ++j)
        bt[(size_t)(n0 + ty + j * 8) * K_ + k0 + tx] =
            f2bf(tile[tx][ty + j * 8]);
}

// ---------------------------------------------------------------------------
// Kernel 2: LayerNorm — exact r0 champion version (block-per-row, plain
// stores). NT stores measured +18.5 µs (r5): ln_bf16 is re-read by the GEMM
// (L2 warmth lost) and NT C-writes expose partial lines to HBM. Reverted.
// ---------------------------------------------------------------------------
__global__ __launch_bounds__(256) void ln_kernel(
    const float* __restrict__ x, const float* __restrict__ scale,
    const float* __restrict__ bias, float* __restrict__ ln_out,
    u16* __restrict__ ln_bf16)
{
    const int row = blockIdx.x;
    const int tid = threadIdx.x;
    const float4 v = reinterpret_cast<const float4*>(x + (size_t)row * H_)[tid];

    float s  = v.x + v.y + v.z + v.w;
    float sq = v.x * v.x + v.y * v.y + v.z * v.z + v.w * v.w;
#pragma unroll
    for (int off = 32; off >= 1; off >>= 1) {
        s  += __shfl_down(s, off, 64);
        sq += __shfl_down(sq, off, 64);
    }
    __shared__ float red[8];
    const int wave = tid >> 6, lane = tid & 63;
    if (lane == 0) { red[wave] = s; red[4 + wave] = sq; }
    __syncthreads();
    const float Ssum = red[0] + red[1] + red[2] + red[3];
    const float Qsum = red[4] + red[5] + red[6] + red[7];
    const float mu   = Ssum * (1.0f / H_);
    const float var  = Qsum * (1.0f / H_) - mu * mu;
    const float rstd = rsqrtf(var + 1e-6f);

    const float4 sc = reinterpret_cast<const float4*>(scale)[tid];
    const float4 bi = reinterpret_cast<const float4*>(bias)[tid];
    float4 y;
    y.x = (v.x - mu) * rstd * sc.x + bi.x;
    y.y = (v.y - mu) * rstd * sc.y + bi.y;
    y.z = (v.z - mu) * rstd * sc.z + bi.z;
    y.w = (v.w - mu) * rstd * sc.w + bi.w;

    reinterpret_cast<float4*>(ln_out + (size_t)row * H_)[tid] = y;

    ushort4 h;
    h.x = f2bf(y.x); h.y = f2bf(y.y); h.z = f2bf(y.z); h.w = f2bf(y.w);
    reinterpret_cast<ushort4*>(ln_bf16 + (size_t)row * H_)[tid] = h;
}

// ---------------------------------------------------------------------------
// Kernel 3: GEMM C = A * Bt^T — r0 champion structure; SINGLE change:
// __launch_bounds__(256, 4) -> VGPR capped at 128/wave -> 4 waves/SIMD ->
// 4 blocks/CU (vs ~3 at the default ~164 VGPR). LDS is 32 KiB/block so 4
// blocks fit (160/32=5). Mechanism: this structure's throughput comes from
// inter-block overlap hiding the per-K-iter vmcnt(0)+barrier drain (m114);
// one more resident block = 33% more drain-hiding work per CU.
// Register budget: acc 64 + af/bf frags 32 + addressing ~25 ~= 121-135;
// staging is global_load_lds (no data VGPRs). If this spills, perf tanks
// visibly (GEMM would enter top-5) -> revert signal.
// ---------------------------------------------------------------------------
__global__ __launch_bounds__(256, 4) void gemm_bt_kernel(
    const u16* __restrict__ A, const u16* __restrict__ Bt,
    float* __restrict__ C)
{
    __shared__ __align__(16) u16 As[BM * BK];
    __shared__ __align__(16) u16 Bs[BN * BK];

    const int tid  = threadIdx.x;
    const int wave = tid >> 6;
    const int lane = tid & 63;
    const int wm   = wave >> 1;  // 0..1
    const int wn   = wave & 1;   // 0..1

    // XCD swizzle: by = (bid>>6)*8 + (bid&7), bx = (bid>>3)&7
    const int bid  = blockIdx.x;
    const int bx   = (bid >> 3) & 7;
    const int by   = ((bid >> 6) << 3) | (bid & 7);
    const int row0 = by * BM;
    const int col0 = bx * BN;

    floatx4 acc[4][4];
#pragma unroll
    for (int i = 0; i < 4; ++i)
#pragma unroll
        for (int j = 0; j < 4; ++j) acc[i][j] = (floatx4)0.0f;

    // staging: per call each wave fills 8 rows (64 lanes * 16B = 8 rows * 128B)
    // lane (r=lane>>3, c=lane&7) fetches global chunk (c ^ r) of row r
    const int srow = wave * 8 + (lane >> 3);             // row within 32-row group
    const int scol = (((lane & 7) ^ (lane >> 3)) * 8);   // swizzled bf16 col
    const u16* Ag = A + (size_t)(row0 + srow) * K_ + scol;
    const u16* Bg = Bt + (size_t)(col0 + srow) * K_ + scol;
    char* AsBase = (char*)As + (size_t)(wave * 8) * (BK * 2);
    char* BsBase = (char*)Bs + (size_t)(wave * 8) * (BK * 2);

    for (int kt = 0; kt < K_ / BK; ++kt) {
        const int k0 = kt * BK;
#pragma unroll
        for (int i = 0; i < 4; ++i) {
            async_load16(Ag + (size_t)(i * 32) * K_ + k0,
                         AsBase + (size_t)(i * 32) * (BK * 2));
            async_load16(Bg + (size_t)(i * 32) * K_ + k0,
                         BsBase + (size_t)(i * 32) * (BK * 2));
        }
        __syncthreads();  // drains vmcnt -> LDS tiles complete

#pragma unroll
        for (int ks = 0; ks < 2; ++ks) {
            short8 af[4], bf[4];
#pragma unroll
            for (int mt = 0; mt < 4; ++mt) {
                const int r = wm * 64 + mt * 16 + (lane & 15);
                const int q = ks * 4 + (lane >> 4);       // 16B chunk index
                const int c = q ^ (r & 7);                // XOR de-swizzle
                af[mt] = *reinterpret_cast<const short8*>(
                    (const char*)As + (size_t)r * (BK * 2) + c * 16);
            }
#pragma unroll
            for (int nt = 0; nt < 4; ++nt) {
                const int r = wn * 64 + nt * 16 + (lane & 15);
                const int q = ks * 4 + (lane >> 4);
                const int c = q ^ (r & 7);
                bf[nt] = *reinterpret_cast<const short8*>(
                    (const char*)Bs + (size_t)r * (BK * 2) + c * 16);
            }
#pragma unroll
            for (int mt = 0; mt < 4; ++mt)
#pragma unroll
                for (int nt = 0; nt < 4; ++nt)
                    acc[mt][nt] = __builtin_amdgcn_mfma_f32_16x16x32_bf16(
                        af[mt], bf[nt], acc[mt][nt], 0, 0, 0);
        }
        __syncthreads();  // protect LDS from next iteration's staging
    }

    // epilogue: C/D layout col = lane&15, row = (lane>>4)*4 + reg
#pragma unroll
    for (int mt = 0; mt < 4; ++mt) {
#pragma unroll
        for (int nt = 0; nt < 4; ++nt) {
            const int r0 = row0 + wm * 64 + mt * 16 + (lane >> 4) * 4;
            const int c  = col0 + wn * 64 + nt * 16 + (lane & 15);
#pragma unroll
            for (int r = 0; r < 4; ++r)
                C[(size_t)(r0 + r) * N_ + c] = acc[mt][nt][r];
        }
    }
}

// ---------------------------------------------------------------------------
extern "C" void kernel_launch(void* const* d_in, const int* in_sizes, int n_in,
                              void* d_out, int out_size, void* d_ws, size_t ws_size,
                              hipStream_t stream) {
    const float* x      = (const float*)d_in[0];   // (S,B,H)
    const float* scale  = (const float*)d_in[1];   // (H,)
    const float* lnbias = (const float*)d_in[2];   // (H,)
    const float* weight = (const float*)d_in[3];   // (H,F)

    float* out    = (float*)d_out;                     // (S,B,F)
    float* ln_out = (float*)d_out + (size_t)M_ * N_;   // (S,B,H)

    // workspace layout: [A bf16: M_*K_ u16 = 64 MiB][Bt bf16: N_*K_ u16 = 2 MiB]
    u16* ln_bf16 = (u16*)d_ws;
    u16* bt      = (u16*)d_ws + (size_t)M_ * K_;

    transpose_cast_kernel<<<dim3(N_ / 32, K_ / 32), dim3(32, 8), 0, stream>>>(
        weight, bt);
    ln_kernel<<<M_, 256, 0, stream>>>(x, scale, lnbias, ln_out, ln_bf16);
    gemm_bt_kernel<<<(M_ / BM) * (N_ / BN), 256, 0, stream>>>(ln_bf16, bt, out);
}